// Round 3
// baseline (553.488 us; speedup 1.0000x reference)
//
#include <hip/hip_runtime.h>
#include <hip/hip_bf16.h>

typedef unsigned short ushort_t;
typedef __attribute__((ext_vector_type(8))) short short8;
typedef short8 __attribute__((may_alias)) short8_ma;
typedef __attribute__((ext_vector_type(4))) float f32x4;
typedef f32x4 __attribute__((may_alias)) f32x4_ma;

__device__ __forceinline__ unsigned short f2bf(float f) {
    union { float f; unsigned int i; } x; x.f = f;
    unsigned int r = x.i + 0x7FFFu + ((x.i >> 16) & 1u);
    return (unsigned short)(r >> 16);
}
__device__ __forceinline__ f32x4 mfma16x16x32(short8 a, short8 b, f32x4 c) {
    return __builtin_amdgcn_mfma_f32_16x16x32_bf16(a, b, c, 0, 0, 0);
}

// ---------------------------------------------------------------------------
// Weight transpose + f32->bf16: Wt[n][k] = bf16(W[k][n]), 1024x1024, 4 matrices
// ---------------------------------------------------------------------------
__global__ __launch_bounds__(256)
void transpose4(const float* __restrict__ W0, const float* __restrict__ W1,
                const float* __restrict__ W2, const float* __restrict__ W3,
                ushort_t* __restrict__ T0, ushort_t* __restrict__ T1,
                ushort_t* __restrict__ T2, ushort_t* __restrict__ T3) {
    __shared__ ushort_t tile[64][65];
    const float* W; ushort_t* T;
    switch (blockIdx.z) {
        case 0: W = W0; T = T0; break;
        case 1: W = W1; T = T1; break;
        case 2: W = W2; T = T2; break;
        default: W = W3; T = T3; break;
    }
    int bx = blockIdx.x * 64, by = blockIdx.y * 64;
    int tx = threadIdx.x & 63, ty = threadIdx.x >> 6;  // 64 x 4
    #pragma unroll
    for (int i = 0; i < 64; i += 4)
        tile[ty + i][tx] = f2bf(W[(size_t)(by + ty + i) * 1024 + bx + tx]);
    __syncthreads();
    #pragma unroll
    for (int i = 0; i < 64; i += 4)
        T[(size_t)(bx + ty + i) * 1024 + by + tx] = tile[tx][ty + i];
}

// ---------------------------------------------------------------------------
// GEMM: C[M,N] = A[M,K] @ Bt[N,K]^T + bias[N]   (bf16 MFMA, fp32 acc)
// A_F32: A is f32 in global, converted to bf16 during LDS staging.
// C_F32: C stored as f32 (no outscale); else bf16 with outscale.
// 256 threads = 4 waves (2x2), block tile 128x128, BK=64. Wave tile 64x64.
// ---------------------------------------------------------------------------
#define BM 128
#define BN 128
#define BK 64
#define LDK 72  // BK + 8 pad; 72*2B = 144B rows (16B-aligned)

template<bool A_F32, bool C_F32>
__global__ __launch_bounds__(256)
void gemm_bt_bias(const void* __restrict__ Aab, const ushort_t* __restrict__ Bt,
                  const float* __restrict__ bias, void* __restrict__ Cab,
                  int M, int N, int K, float outscale) {
    __shared__ __align__(16) ushort_t As[BM * LDK];
    __shared__ __align__(16) ushort_t Bs[BN * LDK];
    const int t = threadIdx.x;
    const int m0 = blockIdx.y * BM;
    const int n0 = blockIdx.x * BN;
    const int w = t >> 6, lane = t & 63, quad = lane >> 4, lr = lane & 15;
    const int wm = (w >> 1) * 64, wn = (w & 1) * 64;

    f32x4 acc[4][4] = {};

    const int srow = t >> 2;        // 0..63
    const int scol = (t & 3) * 8;   // 0,8,16,24

    for (int k0 = 0; k0 < K; k0 += BK) {
        __syncthreads();
        #pragma unroll
        for (int pass = 0; pass < 2; pass++) {
            int row = srow + pass * 64;
            ushort_t* as = As + row * LDK;
            ushort_t* bs = Bs + row * LDK;
            const ushort_t* bg = Bt + (size_t)(n0 + row) * K + k0;
            #pragma unroll
            for (int c = 0; c < 2; c++) {
                int col = scol + c * 32;
                if (A_F32) {
                    const float* ag = (const float*)Aab + (size_t)(m0 + row) * K + k0 + col;
                    f32x4 v0 = *(const f32x4_ma*)(ag);
                    f32x4 v1 = *(const f32x4_ma*)(ag + 4);
                    short8 s;
                    #pragma unroll
                    for (int j = 0; j < 4; j++) {
                        ((ushort_t*)&s)[j]     = f2bf(v0[j]);
                        ((ushort_t*)&s)[4 + j] = f2bf(v1[j]);
                    }
                    *(short8_ma*)(as + col) = s;
                } else {
                    const ushort_t* ag = (const ushort_t*)Aab + (size_t)(m0 + row) * K + k0 + col;
                    *(short8_ma*)(as + col) = *(const short8_ma*)(ag);
                }
                *(short8_ma*)(bs + col) = *(const short8_ma*)(bg + col);
            }
        }
        __syncthreads();
        #pragma unroll
        for (int kc = 0; kc < 2; kc++) {
            short8 af[4], bf[4];
            #pragma unroll
            for (int i = 0; i < 4; i++) {
                af[i] = *(const short8_ma*)(As + (wm + i * 16 + lr) * LDK + kc * 32 + quad * 8);
                bf[i] = *(const short8_ma*)(Bs + (wn + i * 16 + lr) * LDK + kc * 32 + quad * 8);
            }
            #pragma unroll
            for (int i = 0; i < 4; i++)
                #pragma unroll
                for (int j = 0; j < 4; j++)
                    acc[i][j] = mfma16x16x32(af[i], bf[j], acc[i][j]);
        }
    }

    // Epilogue: C/D layout row = quad*4 + reg, col = lane&15
    #pragma unroll
    for (int i = 0; i < 4; i++) {
        int row = m0 + wm + i * 16 + quad * 4;
        #pragma unroll
        for (int j = 0; j < 4; j++) {
            int col = n0 + wn + j * 16 + lr;
            float bv = bias[col];
            #pragma unroll
            for (int r = 0; r < 4; r++) {
                size_t idx = (size_t)(row + r) * N + col;
                if (C_F32) ((float*)Cab)[idx] = acc[i][j][r] + bv;
                else ((ushort_t*)Cab)[idx] = f2bf((acc[i][j][r] + bv) * outscale);
            }
        }
    }
}

// ---------------------------------------------------------------------------
// Flash attention: Q,K,V stored [B*S, 1024] bf16 (head h at cols h*64..h*64+64).
// Q is pre-scaled by 1/8. One WG per (q-tile of 128, b*h). 4 waves; wave w owns
// q rows w*32..w*32+32. K-tiles of 64 rows, 32 iterations.
// Z may alias Q: each block reads exactly the Q region it writes (wave-private
// rows), reads complete before writes.
// ---------------------------------------------------------------------------
#define LDD 72   // 64 + 8 pad (144B rows)

__global__ __launch_bounds__(256)
void attn_fwd(const ushort_t* __restrict__ Q, const ushort_t* __restrict__ Kg,
              const ushort_t* __restrict__ Vg, ushort_t* __restrict__ Z) {
    __shared__ __align__(16) ushort_t Ks[64 * LDD];    // K-tile  [krow][d]
    __shared__ __align__(16) ushort_t Vt[64 * LDD];    // V-tile transposed [d][krow]
    __shared__ __align__(16) ushort_t Ps[128 * LDD];   // P tile  [qrow][krow] (wave-private rows)

    const int t = threadIdx.x;
    const int qt = blockIdx.x;        // 0..15
    const int bh = blockIdx.y;        // 0..63
    const int b = bh >> 4, h = bh & 15;
    const int w = t >> 6, lane = t & 63, quad = lane >> 4, lr = lane & 15;

    const size_t rs = 1024;
    const size_t qbase = ((size_t)b * 2048 + qt * 128) * rs + h * 64;
    const size_t kvbase = ((size_t)b * 2048) * rs + h * 64;

    // Q fragments (A-operand layout: m = lane&15, k = quad*8 + j), persistent
    short8 qf[2][2];
    #pragma unroll
    for (int mt = 0; mt < 2; mt++)
        #pragma unroll
        for (int kc = 0; kc < 2; kc++)
            qf[mt][kc] = *(const short8_ma*)(Q + qbase + (size_t)(w * 32 + mt * 16 + lr) * rs + kc * 32 + quad * 8);

    f32x4 oacc[2][4] = {};
    float mrow[2][4], lrow[2][4];
    #pragma unroll
    for (int mt = 0; mt < 2; mt++)
        #pragma unroll
        for (int r = 0; r < 4; r++) { mrow[mt][r] = -INFINITY; lrow[mt][r] = 0.f; }

    const int srow = t >> 2;         // 0..63
    const int scol = (t & 3) * 8;    // 0,8,16,24

    for (int kt = 0; kt < 32; kt++) {
        __syncthreads();
        // stage K-tile and transposed V-tile
        {
            const ushort_t* kg = Kg + kvbase + (size_t)(kt * 64 + srow) * rs;
            const ushort_t* vg = Vg + kvbase + (size_t)(kt * 64 + srow) * rs;
            ushort_t* ks = Ks + srow * LDD;
            #pragma unroll
            for (int c = 0; c < 2; c++) {
                int col = scol + c * 32;
                *(short8_ma*)(ks + col) = *(const short8_ma*)(kg + col);
                short8 vv = *(const short8_ma*)(vg + col);
                #pragma unroll
                for (int j = 0; j < 8; j++)
                    Vt[(col + j) * LDD + srow] = ((ushort_t*)&vv)[j];
            }
        }
        __syncthreads();

        // S = Q K^T  (S[m=qrow][n=krow]); Q already carries the 1/8 scale
        f32x4 sacc[2][4] = {};
        #pragma unroll
        for (int kc = 0; kc < 2; kc++) {
            short8 kf[4];
            #pragma unroll
            for (int nt = 0; nt < 4; nt++)
                kf[nt] = *(const short8_ma*)(Ks + (nt * 16 + lr) * LDD + kc * 32 + quad * 8);
            #pragma unroll
            for (int mt = 0; mt < 2; mt++)
                #pragma unroll
                for (int nt = 0; nt < 4; nt++)
                    sacc[mt][nt] = mfma16x16x32(qf[mt][kc], kf[nt], sacc[mt][nt]);
        }

        // online softmax (per lane: rows quad*4+r of each mt; cols sampled by lane&15)
        #pragma unroll
        for (int mt = 0; mt < 2; mt++) {
            float mx[4];
            #pragma unroll
            for (int r = 0; r < 4; r++) {
                float m = sacc[mt][0][r];
                #pragma unroll
                for (int nt = 1; nt < 4; nt++) m = fmaxf(m, sacc[mt][nt][r]);
                mx[r] = m;
            }
            #pragma unroll
            for (int off = 1; off < 16; off <<= 1)
                #pragma unroll
                for (int r = 0; r < 4; r++)
                    mx[r] = fmaxf(mx[r], __shfl_xor(mx[r], off, 64));

            float alpha[4], rsum[4];
            #pragma unroll
            for (int r = 0; r < 4; r++) {
                float mnew = fmaxf(mrow[mt][r], mx[r]);
                alpha[r] = __expf(mrow[mt][r] - mnew);
                mrow[mt][r] = mnew;
                rsum[r] = 0.f;
            }
            #pragma unroll
            for (int nt = 0; nt < 4; nt++)
                #pragma unroll
                for (int r = 0; r < 4; r++) {
                    float p = __expf(sacc[mt][nt][r] - mrow[mt][r]);
                    rsum[r] += p;
                    Ps[(w * 32 + mt * 16 + quad * 4 + r) * LDD + nt * 16 + lr] = f2bf(p);
                }
            #pragma unroll
            for (int off = 1; off < 16; off <<= 1)
                #pragma unroll
                for (int r = 0; r < 4; r++)
                    rsum[r] += __shfl_xor(rsum[r], off, 64);
            #pragma unroll
            for (int r = 0; r < 4; r++)
                lrow[mt][r] = lrow[mt][r] * alpha[r] + rsum[r];
            #pragma unroll
            for (int dn = 0; dn < 4; dn++)
                #pragma unroll
                for (int r = 0; r < 4; r++)
                    oacc[mt][dn][r] *= alpha[r];
        }

        // Compiler fence: P writes above are scalar stores, reads below are
        // vector loads — block scheduler/TBAA reordering. HW same-wave DS
        // ordering makes this sufficient (rows are wave-private).
        asm volatile("" ::: "memory");

        // O += P V
        #pragma unroll
        for (int kc2 = 0; kc2 < 2; kc2++) {
            short8 pf[2], vf[4];
            #pragma unroll
            for (int mt = 0; mt < 2; mt++)
                pf[mt] = *(const short8_ma*)(Ps + (w * 32 + mt * 16 + lr) * LDD + kc2 * 32 + quad * 8);
            #pragma unroll
            for (int dn = 0; dn < 4; dn++)
                vf[dn] = *(const short8_ma*)(Vt + (dn * 16 + lr) * LDD + kc2 * 32 + quad * 8);
            #pragma unroll
            for (int mt = 0; mt < 2; mt++)
                #pragma unroll
                for (int dn = 0; dn < 4; dn++)
                    oacc[mt][dn] = mfma16x16x32(pf[mt], vf[dn], oacc[mt][dn]);
        }
    }

    // epilogue: normalize and store
    #pragma unroll
    for (int mt = 0; mt < 2; mt++)
        #pragma unroll
        for (int r = 0; r < 4; r++) {
            float inv = 1.f / lrow[mt][r];
            size_t row = qbase + (size_t)(w * 32 + mt * 16 + quad * 4 + r) * rs;
            #pragma unroll
            for (int dn = 0; dn < 4; dn++)
                Z[row + dn * 16 + lr] = f2bf(oacc[mt][dn][r] * inv);
        }
}

// ---------------------------------------------------------------------------
extern "C" void kernel_launch(void* const* d_in, const int* in_sizes, int n_in,
                              void* d_out, int out_size, void* d_ws, size_t ws_size,
                              hipStream_t stream) {
    const float* query = (const float*)d_in[0];   // [4,2048,1024] f32
    const float* key   = (const float*)d_in[1];
    const float* value = (const float*)d_in[2];
    const float* Wq = (const float*)d_in[3];      // [1024,1024] f32
    const float* bq = (const float*)d_in[4];      // [1024] f32
    const float* Wk = (const float*)d_in[5];
    const float* bk = (const float*)d_in[6];
    const float* Wv = (const float*)d_in[7];
    const float* bv = (const float*)d_in[8];
    const float* Wo = (const float*)d_in[9];
    const float* bo = (const float*)d_in[10];
    float* out = (float*)d_out;                   // [4,2048,1024] f32

    char* ws = (char*)d_ws;
    const size_t WSZ = 1024ull * 1024 * 2;       // 2 MB per transposed bf16 weight
    const size_t QSZ = 8192ull * 1024 * 2;       // 16.8 MB per bf16 activation
    ushort_t* WqT = (ushort_t*)(ws + 0 * WSZ);
    ushort_t* WkT = (ushort_t*)(ws + 1 * WSZ);
    ushort_t* WvT = (ushort_t*)(ws + 2 * WSZ);
    ushort_t* WoT = (ushort_t*)(ws + 3 * WSZ);
    ushort_t* Qws = (ushort_t*)(ws + 4 * WSZ);
    ushort_t* Kws = (ushort_t*)(ws + 4 * WSZ + 1 * QSZ);
    ushort_t* Vws = (ushort_t*)(ws + 4 * WSZ + 2 * QSZ);
    ushort_t* Zws = Qws;  // safe aliasing: see attn_fwd comment

    transpose4<<<dim3(16, 16, 4), 256, 0, stream>>>(Wq, Wk, Wv, Wo, WqT, WkT, WvT, WoT);

    dim3 gg(1024 / BN, 8192 / BM);  // (8, 64)
    // Q projection carries the 1/sqrt(64) = 1/8 softmax scale (exact in bf16)
    gemm_bt_bias<true, false><<<gg, 256, 0, stream>>>(query, WqT, bq, Qws, 8192, 1024, 1024, 0.125f);
    gemm_bt_bias<true, false><<<gg, 256, 0, stream>>>(key,   WkT, bk, Kws, 8192, 1024, 1024, 1.0f);
    gemm_bt_bias<true, false><<<gg, 256, 0, stream>>>(value, WvT, bv, Vws, 8192, 1024, 1024, 1.0f);

    attn_fwd<<<dim3(16, 64), 256, 0, stream>>>(Qws, Kws, Vws, Zws);

    gemm_bt_bias<false, true><<<gg, 256, 0, stream>>>(Zws, WoT, bo, out, 8192, 1024, 1024, 1.0f);
}

// Round 5
// 482.471 us; speedup vs baseline: 1.1472x; 1.1472x over previous
//
#include <hip/hip_runtime.h>
#include <hip/hip_bf16.h>

typedef unsigned short ushort_t;
typedef __attribute__((ext_vector_type(8))) short short8;
typedef short8 __attribute__((may_alias)) short8_ma;
typedef __attribute__((ext_vector_type(4))) float f32x4;
typedef f32x4 __attribute__((may_alias)) f32x4_ma;
typedef __attribute__((ext_vector_type(2))) unsigned int u32x2;
typedef u32x2 __attribute__((may_alias)) u32x2_ma;
typedef __attribute__((ext_vector_type(4))) unsigned int u32x4;
typedef u32x4 __attribute__((may_alias)) u32x4_ma;

#if __has_builtin(__builtin_amdgcn_exp2f)
#define EXP2(x) __builtin_amdgcn_exp2f(x)
#else
#define EXP2(x) exp2f(x)
#endif

__device__ __forceinline__ unsigned short f2bf(float f) {
    union { float f; unsigned int i; } x; x.f = f;
    unsigned int r = x.i + 0x7FFFu + ((x.i >> 16) & 1u);
    return (unsigned short)(r >> 16);
}
// RNE-rounded pair of bf16 packed in a u32: [lo, hi] in memory order.
__device__ __forceinline__ unsigned int bfround(float f) {
    union { float f; unsigned int i; } x; x.f = f;
    return x.i + 0x7FFFu + ((x.i >> 16) & 1u);
}
__device__ __forceinline__ unsigned int pack2bf(float lo, float hi) {
    return __builtin_amdgcn_perm(bfround(hi), bfround(lo), 0x07060302u);
}
__device__ __forceinline__ f32x4 mfma16x16x32(short8 a, short8 b, f32x4 c) {
    return __builtin_amdgcn_mfma_f32_16x16x32_bf16(a, b, c, 0, 0, 0);
}

// ---------------------------------------------------------------------------
// Weight transpose + f32->bf16: Wt[n][k] = bf16(W[k][n]), 1024x1024, 4 matrices
// ---------------------------------------------------------------------------
__global__ __launch_bounds__(256)
void transpose4(const float* __restrict__ W0, const float* __restrict__ W1,
                const float* __restrict__ W2, const float* __restrict__ W3,
                ushort_t* __restrict__ T0, ushort_t* __restrict__ T1,
                ushort_t* __restrict__ T2, ushort_t* __restrict__ T3) {
    __shared__ ushort_t tile[64][65];
    const float* W; ushort_t* T;
    switch (blockIdx.z) {
        case 0: W = W0; T = T0; break;
        case 1: W = W1; T = T1; break;
        case 2: W = W2; T = T2; break;
        default: W = W3; T = T3; break;
    }
    int bx = blockIdx.x * 64, by = blockIdx.y * 64;
    int tx = threadIdx.x & 63, ty = threadIdx.x >> 6;  // 64 x 4
    #pragma unroll
    for (int i = 0; i < 64; i += 4)
        tile[ty + i][tx] = f2bf(W[(size_t)(by + ty + i) * 1024 + bx + tx]);
    __syncthreads();
    #pragma unroll
    for (int i = 0; i < 64; i += 4)
        T[(size_t)(bx + ty + i) * 1024 + by + tx] = tile[tx][ty + i];
}

// ---------------------------------------------------------------------------
// GEMM: C[M,N] = A[M,K] @ Bt[N,K]^T + bias[N]   (bf16 MFMA, fp32 acc)
// ---------------------------------------------------------------------------
#define BM 128
#define BN 128
#define BK 64
#define LDK 72  // BK + 8 pad; 144B rows (16B-aligned)

template<bool A_F32, bool C_F32>
__global__ __launch_bounds__(256)
void gemm_bt_bias(const void* __restrict__ Aab, const ushort_t* __restrict__ Bt,
                  const float* __restrict__ bias, void* __restrict__ Cab,
                  int M, int N, int K, float outscale) {
    __shared__ __align__(16) ushort_t As[BM * LDK];
    __shared__ __align__(16) ushort_t Bs[BN * LDK];
    const int t = threadIdx.x;
    const int m0 = blockIdx.y * BM;
    const int n0 = blockIdx.x * BN;
    const int w = t >> 6, lane = t & 63, quad = lane >> 4, lr = lane & 15;
    const int wm = (w >> 1) * 64, wn = (w & 1) * 64;

    f32x4 acc[4][4] = {};

    const int srow = t >> 2;        // 0..63
    const int scol = (t & 3) * 8;   // 0,8,16,24

    for (int k0 = 0; k0 < K; k0 += BK) {
        __syncthreads();
        #pragma unroll
        for (int pass = 0; pass < 2; pass++) {
            int row = srow + pass * 64;
            ushort_t* as = As + row * LDK;
            ushort_t* bs = Bs + row * LDK;
            const ushort_t* bg = Bt + (size_t)(n0 + row) * K + k0;
            #pragma unroll
            for (int c = 0; c < 2; c++) {
                int col = scol + c * 32;
                if (A_F32) {
                    const float* ag = (const float*)Aab + (size_t)(m0 + row) * K + k0 + col;
                    f32x4 v0 = *(const f32x4_ma*)(ag);
                    f32x4 v1 = *(const f32x4_ma*)(ag + 4);
                    u32x4 pk;
                    pk[0] = pack2bf(v0[0], v0[1]);
                    pk[1] = pack2bf(v0[2], v0[3]);
                    pk[2] = pack2bf(v1[0], v1[1]);
                    pk[3] = pack2bf(v1[2], v1[3]);
                    *(u32x4_ma*)(as + col) = pk;
                } else {
                    const ushort_t* ag = (const ushort_t*)Aab + (size_t)(m0 + row) * K + k0 + col;
                    *(short8_ma*)(as + col) = *(const short8_ma*)(ag);
                }
                *(short8_ma*)(bs + col) = *(const short8_ma*)(bg + col);
            }
        }
        __syncthreads();
        #pragma unroll
        for (int kc = 0; kc < 2; kc++) {
            short8 af[4], bf[4];
            #pragma unroll
            for (int i = 0; i < 4; i++) {
                af[i] = *(const short8_ma*)(As + (wm + i * 16 + lr) * LDK + kc * 32 + quad * 8);
                bf[i] = *(const short8_ma*)(Bs + (wn + i * 16 + lr) * LDK + kc * 32 + quad * 8);
            }
            #pragma unroll
            for (int i = 0; i < 4; i++)
                #pragma unroll
                for (int j = 0; j < 4; j++)
                    acc[i][j] = mfma16x16x32(af[i], bf[j], acc[i][j]);
        }
    }

    // Epilogue: C/D layout row = quad*4 + reg, col = lane&15
    #pragma unroll
    for (int i = 0; i < 4; i++) {
        int row = m0 + wm + i * 16 + quad * 4;
        #pragma unroll
        for (int j = 0; j < 4; j++) {
            int col = n0 + wn + j * 16 + lr;
            float bv = bias[col];
            #pragma unroll
            for (int r = 0; r < 4; r++) {
                size_t idx = (size_t)(row + r) * N + col;
                if (C_F32) ((float*)Cab)[idx] = acc[i][j][r] + bv;
                else ((ushort_t*)Cab)[idx] = f2bf((acc[i][j][r] + bv) * outscale);
            }
        }
    }
}

// ---------------------------------------------------------------------------
// Flash attention v2 — S^T formulation.
// Q pre-scaled by 0.125*log2(e); softmax in exp2 domain.
// S^T = K·Q^T via MFMA (operand swap): per lane, P values are 4 consecutive
// krows (quad*4+r) at fixed qrow (lane&15) -> in-lane reductions + vector
// ds_write_b64 of P. Vt staged with XOR-swizzled chunks to kill the 8-way
// write conflicts. Z may alias Q (wave reads exactly the rows it later writes).
// ---------------------------------------------------------------------------
#define LDD 72   // row stride for Ks/Vt/Ps (144B)

__global__ __launch_bounds__(256)
void attn_fwd(const ushort_t* __restrict__ Q, const ushort_t* __restrict__ Kg,
              const ushort_t* __restrict__ Vg, ushort_t* __restrict__ Z) {
    __shared__ __align__(16) ushort_t Ks[64 * LDD];    // [krow][d], row-major
    __shared__ __align__(16) ushort_t Vt[64 * LDD];    // [d][krow-chunk swizzled]
    __shared__ __align__(16) ushort_t Ps[128 * LDD];   // [qrow][krow-chunk swizzled]

    const int t = threadIdx.x;
    const int qt = blockIdx.x;        // 0..15
    const int bh = blockIdx.y;        // 0..63
    const int b = bh >> 4, h = bh & 15;
    const int w = t >> 6, lane = t & 63, quad = lane >> 4, lr = lane & 15;

    const size_t rs = 1024;
    const size_t qbase = ((size_t)b * 2048 + qt * 128) * rs + h * 64;
    const size_t kvbase = ((size_t)b * 2048) * rs + h * 64;

    // Q fragments (B-operand of S^T = K·Q^T: n = lane&15 = qrow, k = quad*8+j = d)
    short8 qf[2][2];
    #pragma unroll
    for (int mt = 0; mt < 2; mt++)
        #pragma unroll
        for (int kc = 0; kc < 2; kc++)
            qf[mt][kc] = *(const short8_ma*)(Q + qbase + (size_t)(w * 32 + mt * 16 + lr) * rs + kc * 32 + quad * 8);

    f32x4 oacc[2][4] = {};
    float mrow[2] = { -INFINITY, -INFINITY };
    float lrow[2] = { 0.f, 0.f };

    const int srow = t >> 2;         // 0..63 (krow for staging)
    const int a4 = t & 3;
    const int scol = a4 * 8;

    for (int kt = 0; kt < 32; kt++) {
        __syncthreads();
        // stage K-tile (row-major) and swizzled V^T tile
        {
            const ushort_t* kg = Kg + kvbase + (size_t)(kt * 64 + srow) * rs;
            const ushort_t* vg = Vg + kvbase + (size_t)(kt * 64 + srow) * rs;
            ushort_t* ks = Ks + srow * LDD;
            #pragma unroll
            for (int c = 0; c < 2; c++) {
                int col = scol + c * 32;
                *(short8_ma*)(ks + col) = *(const short8_ma*)(kg + col);
                short8 vv = *(const short8_ma*)(vg + col);
                #pragma unroll
                for (int j = 0; j < 8; j++) {
                    int d = col + j;                               // d&7 == j, d>>3 == a4+4c
                    int phys = (srow >> 3) ^ j ^ (a4 + 4 * c);     // chunk swizzle
                    Vt[d * LDD + phys * 8 + (srow & 7)] = ((ushort_t*)&vv)[j];
                }
            }
        }
        __syncthreads();

        // S^T = K·Q^T : sacc[nt][mt] rows = krow (nt*16+quad*4+r), cols = qrow (mt*16+lr)
        f32x4 sacc[4][2] = {};
        #pragma unroll
        for (int kc = 0; kc < 2; kc++) {
            short8 kf[4];
            #pragma unroll
            for (int nt = 0; nt < 4; nt++)
                kf[nt] = *(const short8_ma*)(Ks + (nt * 16 + lr) * LDD + kc * 32 + quad * 8);
            #pragma unroll
            for (int nt = 0; nt < 4; nt++)
                #pragma unroll
                for (int mt = 0; mt < 2; mt++)
                    sacc[nt][mt] = mfma16x16x32(kf[nt], qf[mt][kc], sacc[nt][mt]);
        }

        // online softmax per qrow (= mt*16 + lr); 16 values in-lane + cross-quad
        #pragma unroll
        for (int mt = 0; mt < 2; mt++) {
            float mx = sacc[0][mt][0];
            #pragma unroll
            for (int nt = 0; nt < 4; nt++)
                #pragma unroll
                for (int r = 0; r < 4; r++)
                    mx = fmaxf(mx, sacc[nt][mt][r]);
            mx = fmaxf(mx, __shfl_xor(mx, 16, 64));
            mx = fmaxf(mx, __shfl_xor(mx, 32, 64));

            float mnew = fmaxf(mrow[mt], mx);
            float alpha = EXP2(mrow[mt] - mnew);
            mrow[mt] = mnew;

            float rsum = 0.f;
            const int prow = w * 32 + mt * 16 + lr;
            #pragma unroll
            for (int nt = 0; nt < 4; nt++) {
                float p0 = EXP2(sacc[nt][mt][0] - mnew);
                float p1 = EXP2(sacc[nt][mt][1] - mnew);
                float p2 = EXP2(sacc[nt][mt][2] - mnew);
                float p3 = EXP2(sacc[nt][mt][3] - mnew);
                rsum += (p0 + p1) + (p2 + p3);
                u32x2 pw;
                pw[0] = pack2bf(p0, p1);
                pw[1] = pack2bf(p2, p3);
                int chunk = (2 * nt + (quad >> 1)) ^ (lr & 7);
                *(u32x2_ma*)(Ps + prow * LDD + chunk * 8 + (quad & 1) * 4) = pw;
            }
            rsum += __shfl_xor(rsum, 16, 64);
            rsum += __shfl_xor(rsum, 32, 64);
            lrow[mt] = lrow[mt] * alpha + rsum;

            // rescale O rows of this mt block: row = mt*16 + quad*4 + r
            float ab[4];
            #pragma unroll
            for (int r = 0; r < 4; r++)
                ab[r] = __shfl(alpha, quad * 4 + r, 16);
            #pragma unroll
            for (int dn = 0; dn < 4; dn++)
                #pragma unroll
                for (int r = 0; r < 4; r++)
                    oacc[mt][dn][r] *= ab[r];
        }

        // order P writes before P reads (same-wave DS pipe is in-order)
        asm volatile("" ::: "memory");

        // O += P·V
        #pragma unroll
        for (int kc2 = 0; kc2 < 2; kc2++) {
            short8 pf[2], vf[4];
            #pragma unroll
            for (int mt = 0; mt < 2; mt++) {
                int ph = (4 * kc2 + quad) ^ (lr & 7);
                pf[mt] = *(const short8_ma*)(Ps + (w * 32 + mt * 16 + lr) * LDD + ph * 8);
            }
            #pragma unroll
            for (int dn = 0; dn < 4; dn++) {
                int ph = (4 * kc2 + quad) ^ (lr & 7) ^ ((2 * dn + (lr >> 3)) & 7);
                vf[dn] = *(const short8_ma*)(Vt + (dn * 16 + lr) * LDD + ph * 8);
            }
            #pragma unroll
            for (int mt = 0; mt < 2; mt++)
                #pragma unroll
                for (int dn = 0; dn < 4; dn++)
                    oacc[mt][dn] = mfma16x16x32(pf[mt], vf[dn], oacc[mt][dn]);
        }
    }

    // epilogue: normalize (broadcast l per row) and store
    #pragma unroll
    for (int mt = 0; mt < 2; mt++)
        #pragma unroll
        for (int r = 0; r < 4; r++) {
            float lb = __shfl(lrow[mt], quad * 4 + r, 16);
            float inv = 1.f / lb;
            size_t row = qbase + (size_t)(w * 32 + mt * 16 + quad * 4 + r) * rs;
            #pragma unroll
            for (int dn = 0; dn < 4; dn++)
                Z[row + dn * 16 + lr] = f2bf(oacc[mt][dn][r] * inv);
        }
}

// ---------------------------------------------------------------------------
extern "C" void kernel_launch(void* const* d_in, const int* in_sizes, int n_in,
                              void* d_out, int out_size, void* d_ws, size_t ws_size,
                              hipStream_t stream) {
    const float* query = (const float*)d_in[0];   // [4,2048,1024] f32
    const float* key   = (const float*)d_in[1];
    const float* value = (const float*)d_in[2];
    const float* Wq = (const float*)d_in[3];
    const float* bq = (const float*)d_in[4];
    const float* Wk = (const float*)d_in[5];
    const float* bk = (const float*)d_in[6];
    const float* Wv = (const float*)d_in[7];
    const float* bv = (const float*)d_in[8];
    const float* Wo = (const float*)d_in[9];
    const float* bo = (const float*)d_in[10];
    float* out = (float*)d_out;

    char* ws = (char*)d_ws;
    const size_t WSZ = 1024ull * 1024 * 2;
    const size_t QSZ = 8192ull * 1024 * 2;
    ushort_t* WqT = (ushort_t*)(ws + 0 * WSZ);
    ushort_t* WkT = (ushort_t*)(ws + 1 * WSZ);
    ushort_t* WvT = (ushort_t*)(ws + 2 * WSZ);
    ushort_t* WoT = (ushort_t*)(ws + 3 * WSZ);
    ushort_t* Qws = (ushort_t*)(ws + 4 * WSZ);
    ushort_t* Kws = (ushort_t*)(ws + 4 * WSZ + 1 * QSZ);
    ushort_t* Vws = (ushort_t*)(ws + 4 * WSZ + 2 * QSZ);
    ushort_t* Zws = Qws;  // safe aliasing: see attn_fwd comment

    transpose4<<<dim3(16, 16, 4), 256, 0, stream>>>(Wq, Wk, Wv, Wo, WqT, WkT, WvT, WoT);

    dim3 gg(1024 / BN, 8192 / BM);  // (8, 64)
    // Q projection carries 1/sqrt(64) * log2(e): softmax runs in exp2 domain
    gemm_bt_bias<true, false><<<gg, 256, 0, stream>>>(query, WqT, bq, Qws, 8192, 1024, 1024, 0.125f * 1.4426950408889634f);
    gemm_bt_bias<true, false><<<gg, 256, 0, stream>>>(key,   WkT, bk, Kws, 8192, 1024, 1024, 1.0f);
    gemm_bt_bias<true, false><<<gg, 256, 0, stream>>>(value, WvT, bv, Vws, 8192, 1024, 1024, 1.0f);

    attn_fwd<<<dim3(16, 64), 256, 0, stream>>>(Qws, Kws, Vws, Zws);

    gemm_bt_bias<false, true><<<gg, 256, 0, stream>>>(Zws, WoT, bo, out, 8192, 1024, 1024, 1.0f);
}

// Round 6
// 423.224 us; speedup vs baseline: 1.3078x; 1.1400x over previous
//
#include <hip/hip_runtime.h>
#include <hip/hip_bf16.h>

typedef unsigned short ushort_t;
typedef unsigned int u32;
typedef __attribute__((ext_vector_type(8))) short short8;
typedef short8 __attribute__((may_alias)) short8_ma;
typedef __attribute__((ext_vector_type(4))) float f32x4;
typedef f32x4 __attribute__((may_alias)) f32x4_ma;
typedef __attribute__((ext_vector_type(2))) unsigned int u32x2;
typedef u32x2 __attribute__((may_alias)) u32x2_ma;
typedef __attribute__((ext_vector_type(4))) unsigned int u32x4;
typedef u32x4 __attribute__((may_alias)) u32x4_ma;

#if __has_builtin(__builtin_amdgcn_exp2f)
#define EXP2(x) __builtin_amdgcn_exp2f(x)
#else
#define EXP2(x) exp2f(x)
#endif

__device__ __forceinline__ unsigned short f2bf(float f) {
    union { float f; unsigned int i; } x; x.f = f;
    unsigned int r = x.i + 0x7FFFu + ((x.i >> 16) & 1u);
    return (unsigned short)(r >> 16);
}
__device__ __forceinline__ unsigned int bfround(float f) {
    union { float f; unsigned int i; } x; x.f = f;
    return x.i + 0x7FFFu + ((x.i >> 16) & 1u);
}
// RNE bf16 pair packed in u32: [lo, hi] in memory order.
__device__ __forceinline__ unsigned int pack2bf(float lo, float hi) {
    return __builtin_amdgcn_perm(bfround(hi), bfround(lo), 0x07060302u);
}
__device__ __forceinline__ f32x4 mfma16x16x32(short8 a, short8 b, f32x4 c) {
    return __builtin_amdgcn_mfma_f32_16x16x32_bf16(a, b, c, 0, 0, 0);
}
// Async global->LDS, 16B per lane. LDS dest = (wave-uniform base) + lane*16.
typedef const __attribute__((address_space(1))) u32 gu32;
typedef __attribute__((address_space(3))) u32 lu32;
__device__ __forceinline__ void async16(const ushort_t* g, ushort_t* l) {
    __builtin_amdgcn_global_load_lds((gu32*)g, (lu32*)l, 16, 0, 0);
}

// ---------------------------------------------------------------------------
// cast3: f32 -> bf16, 8 elements/thread, 3 tensors via blockIdx.z
// ---------------------------------------------------------------------------
__global__ __launch_bounds__(256)
void cast3(const float* __restrict__ A0, const float* __restrict__ A1,
           const float* __restrict__ A2, ushort_t* __restrict__ O0,
           ushort_t* __restrict__ O1, ushort_t* __restrict__ O2) {
    const float* A; ushort_t* O;
    switch (blockIdx.z) {
        case 0: A = A0; O = O0; break;
        case 1: A = A1; O = O1; break;
        default: A = A2; O = O2; break;
    }
    size_t idx = ((size_t)blockIdx.x * 256 + threadIdx.x) * 8;
    f32x4 v0 = *(const f32x4_ma*)(A + idx);
    f32x4 v1 = *(const f32x4_ma*)(A + idx + 4);
    u32x4 pk;
    pk[0] = pack2bf(v0[0], v0[1]);
    pk[1] = pack2bf(v0[2], v0[3]);
    pk[2] = pack2bf(v1[0], v1[1]);
    pk[3] = pack2bf(v1[2], v1[3]);
    *(u32x4_ma*)(O + idx) = pk;
}

// ---------------------------------------------------------------------------
// Weight transpose + f32->bf16: Wt[n][k] = bf16(W[k][n]), 1024x1024, 4 matrices
// ---------------------------------------------------------------------------
__global__ __launch_bounds__(256)
void transpose4(const float* __restrict__ W0, const float* __restrict__ W1,
                const float* __restrict__ W2, const float* __restrict__ W3,
                ushort_t* __restrict__ T0, ushort_t* __restrict__ T1,
                ushort_t* __restrict__ T2, ushort_t* __restrict__ T3) {
    __shared__ ushort_t tile[64][65];
    const float* W; ushort_t* T;
    switch (blockIdx.z) {
        case 0: W = W0; T = T0; break;
        case 1: W = W1; T = T1; break;
        case 2: W = W2; T = T2; break;
        default: W = W3; T = T3; break;
    }
    int bx = blockIdx.x * 64, by = blockIdx.y * 64;
    int tx = threadIdx.x & 63, ty = threadIdx.x >> 6;
    #pragma unroll
    for (int i = 0; i < 64; i += 4)
        tile[ty + i][tx] = f2bf(W[(size_t)(by + ty + i) * 1024 + bx + tx]);
    __syncthreads();
    #pragma unroll
    for (int i = 0; i < 64; i += 4)
        T[(size_t)(bx + ty + i) * 1024 + by + tx] = tile[tx][ty + i];
}

// ---------------------------------------------------------------------------
// vtrans: per (b,h) transpose V head-slice [2048 kr][64 d] -> VtG [64 d][2048 kr]
// ---------------------------------------------------------------------------
__global__ __launch_bounds__(256)
void vtrans(const ushort_t* __restrict__ V, ushort_t* __restrict__ VtG) {
    __shared__ ushort_t tile[64][65];
    int kt = blockIdx.x;          // 0..31
    int bh = blockIdx.y;          // 0..63
    int b = bh >> 4, h = bh & 15;
    int tx = threadIdx.x & 63, ty = threadIdx.x >> 6;
    #pragma unroll
    for (int i = 0; i < 64; i += 4)
        tile[ty + i][tx] = V[(size_t)(b * 2048 + kt * 64 + ty + i) * 1024 + h * 64 + tx];
    __syncthreads();
    #pragma unroll
    for (int i = 0; i < 64; i += 4)
        VtG[((size_t)bh * 64 + ty + i) * 2048 + kt * 64 + tx] = tile[tx][ty + i];
}

// ---------------------------------------------------------------------------
// GEMM (all-bf16 inputs): C[M,N] = A[M,K] @ Bt[N,K]^T + bias[N]
// Async global_load_lds staging into unpadded 128B LDS rows with gptr-side
// chunk swizzle: chunk c of row r lives at slot c ^ (r&7). b128 fragment reads
// then hit exactly 8 accesses/bank (minimum) -> conflict-free (enumerated).
// ---------------------------------------------------------------------------
template<bool C_F32>
__global__ __launch_bounds__(256)
void gemm_async(const ushort_t* __restrict__ A, const ushort_t* __restrict__ Bt,
                const float* __restrict__ bias, void* __restrict__ Cab,
                int M, int N, int K, float outscale) {
    __shared__ __align__(16) ushort_t As[128 * 64];
    __shared__ __align__(16) ushort_t Bs[128 * 64];
    const int t = threadIdx.x;
    const int m0 = blockIdx.y * 128, n0 = blockIdx.x * 128;
    const int w = t >> 6, lane = t & 63, quad = lane >> 4, lr = lane & 15;
    const int wm = (w >> 1) * 64, wn = (w & 1) * 64;
    const int lrow8 = lane >> 3, lchunk = lane & 7;

    f32x4 acc[4][4] = {};

    for (int k0 = 0; k0 < K; k0 += 64) {
        __syncthreads();
        #pragma unroll
        for (int i = 0; i < 4; i++) {
            int ra = 32 * w + 8 * i + lrow8;           // ra&7 == lrow8
            int sw = (lchunk ^ lrow8) * 8;
            async16(A  + (size_t)(m0 + ra) * K + k0 + sw, &As[(32 * w + 8 * i) * 64]);
            async16(Bt + (size_t)(n0 + ra) * K + k0 + sw, &Bs[(32 * w + 8 * i) * 64]);
        }
        __syncthreads();
        #pragma unroll
        for (int kc = 0; kc < 2; kc++) {
            short8 af[4], bf[4];
            int pa = ((4 * kc + quad) ^ (lr & 7)) * 8;
            #pragma unroll
            for (int i = 0; i < 4; i++) {
                af[i] = *(const short8_ma*)(As + (wm + i * 16 + lr) * 64 + pa);
                bf[i] = *(const short8_ma*)(Bs + (wn + i * 16 + lr) * 64 + pa);
            }
            #pragma unroll
            for (int i = 0; i < 4; i++)
                #pragma unroll
                for (int j = 0; j < 4; j++)
                    acc[i][j] = mfma16x16x32(af[i], bf[j], acc[i][j]);
        }
    }

    // Epilogue: C/D layout row = quad*4 + reg, col = lane&15
    #pragma unroll
    for (int i = 0; i < 4; i++) {
        int row = m0 + wm + i * 16 + quad * 4;
        #pragma unroll
        for (int j = 0; j < 4; j++) {
            int col = n0 + wn + j * 16 + lr;
            float bv = bias[col];
            #pragma unroll
            for (int r = 0; r < 4; r++) {
                size_t idx = (size_t)(row + r) * N + col;
                if (C_F32) ((float*)Cab)[idx] = acc[i][j][r] + bv;
                else ((ushort_t*)Cab)[idx] = f2bf((acc[i][j][r] + bv) * outscale);
            }
        }
    }
}

// ---------------------------------------------------------------------------
// Flash attention v3: S^T = K.Q^T, O^T = V^T.P^T (alpha/l per-lane).
// K staged async from Kws rows; V staged async from pre-transposed VtG rows.
// LDS rows 128B unpadded with chunk^row&7 swizzle (conflict-free reads).
// P^T round-trips through Pt (wave-private rows). Epilogue transposes O^T
// through LDS (Pt reuse) for coalesced global stores. Z may alias Q.
// ---------------------------------------------------------------------------
__global__ __launch_bounds__(256)
void attn_fwd(const ushort_t* __restrict__ Q, const ushort_t* __restrict__ Kg,
              const ushort_t* __restrict__ VtG, ushort_t* __restrict__ Z) {
    __shared__ __align__(16) ushort_t Ks[64 * 64];   // [krow][d]
    __shared__ __align__(16) ushort_t Vt[64 * 64];   // [d][krow]
    __shared__ __align__(16) ushort_t Pt[128 * 64];  // [qrow][krow]

    const int t = threadIdx.x;
    const int qt = blockIdx.x;        // 0..15
    const int bh = blockIdx.y;        // 0..63
    const int b = bh >> 4, h = bh & 15;
    const int w = t >> 6, lane = t & 63, quad = lane >> 4, lr = lane & 15;
    const int lrow8 = lane >> 3, lchunk = lane & 7;

    const size_t rs = 1024;
    const size_t qbase = ((size_t)b * 2048 + qt * 128) * rs + h * 64;
    const size_t kvbase = ((size_t)b * 2048) * rs + h * 64;
    const size_t vbase = (size_t)bh * 64 * 2048;

    // Q fragments (B-operand of S^T: n = lr = qrow, k = quad*8+j = d)
    short8 qf[2][2];
    #pragma unroll
    for (int mt = 0; mt < 2; mt++)
        #pragma unroll
        for (int kc = 0; kc < 2; kc++)
            qf[mt][kc] = *(const short8_ma*)(Q + qbase + (size_t)(w * 32 + mt * 16 + lr) * rs + kc * 32 + quad * 8);

    f32x4 oacc[2][4] = {};   // oacc[mt][dn] = O^T[d = dn*16+quad*4+r][qrow = w*32+mt*16+lr]
    float mrow[2] = { -INFINITY, -INFINITY };
    float lrow[2] = { 0.f, 0.f };

    for (int kt = 0; kt < 32; kt++) {
        __syncthreads();
        #pragma unroll
        for (int i = 0; i < 2; i++) {
            int rloc = 16 * w + 8 * i + lrow8;         // rloc&7 == lrow8
            int sw = (lchunk ^ lrow8) * 8;
            async16(Kg + kvbase + (size_t)(kt * 64 + rloc) * rs + sw, &Ks[(16 * w + 8 * i) * 64]);
            async16(VtG + vbase + (size_t)rloc * 2048 + kt * 64 + sw, &Vt[(16 * w + 8 * i) * 64]);
        }
        __syncthreads();

        // S^T = K.Q^T : sacc[nt][mt] rows = krow (nt*16+quad*4+r), cols = qrow (mt*16+lr)
        f32x4 sacc[4][2] = {};
        #pragma unroll
        for (int kc = 0; kc < 2; kc++) {
            short8 kf[4];
            int pa = ((4 * kc + quad) ^ (lr & 7)) * 8;
            #pragma unroll
            for (int nt = 0; nt < 4; nt++)
                kf[nt] = *(const short8_ma*)(Ks + (nt * 16 + lr) * 64 + pa);
            #pragma unroll
            for (int nt = 0; nt < 4; nt++)
                #pragma unroll
                for (int mt = 0; mt < 2; mt++)
                    sacc[nt][mt] = mfma16x16x32(kf[nt], qf[mt][kc], sacc[nt][mt]);
        }

        // online softmax per qrow (per-lane: qrow = w*32+mt*16+lr)
        #pragma unroll
        for (int mt = 0; mt < 2; mt++) {
            float mx = sacc[0][mt][0];
            #pragma unroll
            for (int nt = 0; nt < 4; nt++)
                #pragma unroll
                for (int r = 0; r < 4; r++)
                    mx = fmaxf(mx, sacc[nt][mt][r]);
            mx = fmaxf(mx, __shfl_xor(mx, 16, 64));
            mx = fmaxf(mx, __shfl_xor(mx, 32, 64));

            float mnew = fmaxf(mrow[mt], mx);
            float alpha = EXP2(mrow[mt] - mnew);
            mrow[mt] = mnew;

            float rsum = 0.f;
            const int prow = w * 32 + mt * 16 + lr;
            #pragma unroll
            for (int nt = 0; nt < 4; nt++) {
                float p0 = EXP2(sacc[nt][mt][0] - mnew);
                float p1 = EXP2(sacc[nt][mt][1] - mnew);
                float p2 = EXP2(sacc[nt][mt][2] - mnew);
                float p3 = EXP2(sacc[nt][mt][3] - mnew);
                rsum += (p0 + p1) + (p2 + p3);
                u32x2 pw;
                pw[0] = pack2bf(p0, p1);
                pw[1] = pack2bf(p2, p3);
                int phys = (2 * nt + (quad >> 1)) ^ (lr & 7);
                *(u32x2_ma*)(Pt + prow * 64 + phys * 8 + (quad & 1) * 4) = pw;
            }
            rsum += __shfl_xor(rsum, 16, 64);
            rsum += __shfl_xor(rsum, 32, 64);
            lrow[mt] = lrow[mt] * alpha + rsum;

            oacc[mt][0] *= alpha;  // O^T cols are qrow=lr -> alpha is per-lane
            oacc[mt][1] *= alpha;
            oacc[mt][2] *= alpha;
            oacc[mt][3] *= alpha;
        }

        // order P writes before P reads (same-wave DS pipe is in-order)
        asm volatile("" ::: "memory");

        // O^T += V^T.P^T  (A = V^T frag, B = P^T frag)
        #pragma unroll
        for (int kc2 = 0; kc2 < 2; kc2++) {
            short8 pf[2], vf[4];
            int pp = ((4 * kc2 + quad) ^ (lr & 7)) * 8;
            #pragma unroll
            for (int mt = 0; mt < 2; mt++)
                pf[mt] = *(const short8_ma*)(Pt + (w * 32 + mt * 16 + lr) * 64 + pp);
            #pragma unroll
            for (int dn = 0; dn < 4; dn++)
                vf[dn] = *(const short8_ma*)(Vt + (dn * 16 + lr) * 64 + pp);
            #pragma unroll
            for (int mt = 0; mt < 2; mt++)
                #pragma unroll
                for (int dn = 0; dn < 4; dn++)
                    oacc[mt][dn] = mfma16x16x32(vf[dn], pf[mt], oacc[mt][dn]);
        }
    }

    // Epilogue: normalize (per-lane l), transpose O^T through LDS, store coalesced.
    ushort_t* Ot = Pt;  // reuse; rows are wave-private (qrows w*32..w*32+31)
    float inv[2] = { 1.f / lrow[0], 1.f / lrow[1] };
    asm volatile("" ::: "memory");
    #pragma unroll
    for (int mt = 0; mt < 2; mt++)
        #pragma unroll
        for (int dn = 0; dn < 4; dn++) {
            u32x2 pw;
            pw[0] = pack2bf(oacc[mt][dn][0] * inv[mt], oacc[mt][dn][1] * inv[mt]);
            pw[1] = pack2bf(oacc[mt][dn][2] * inv[mt], oacc[mt][dn][3] * inv[mt]);
            int phys = (2 * dn + (quad >> 1)) ^ (lr & 7);
            *(u32x2_ma*)(Ot + (w * 32 + mt * 16 + lr) * 64 + phys * 8 + (quad & 1) * 4) = pw;
        }
    asm volatile("" ::: "memory");
    {
        int qrow = t >> 1;            // wave w reads back its own rows 32w..32w+31
        int dhalf = (t & 1) * 32;
        #pragma unroll
        for (int cc = 0; cc < 4; cc++) {
            int phys = ((4 * (t & 1) + cc) ^ (qrow & 7)) * 8;
            short8 v = *(const short8_ma*)(Ot + qrow * 64 + phys);
            *(short8_ma*)(Z + qbase + (size_t)qrow * rs + dhalf + cc * 8) = v;
        }
    }
}

// ---------------------------------------------------------------------------
extern "C" void kernel_launch(void* const* d_in, const int* in_sizes, int n_in,
                              void* d_out, int out_size, void* d_ws, size_t ws_size,
                              hipStream_t stream) {
    const float* query = (const float*)d_in[0];
    const float* key   = (const float*)d_in[1];
    const float* value = (const float*)d_in[2];
    const float* Wq = (const float*)d_in[3];
    const float* bq = (const float*)d_in[4];
    const float* Wk = (const float*)d_in[5];
    const float* bk = (const float*)d_in[6];
    const float* Wv = (const float*)d_in[7];
    const float* bv = (const float*)d_in[8];
    const float* Wo = (const float*)d_in[9];
    const float* bo = (const float*)d_in[10];
    float* out = (float*)d_out;

    char* ws = (char*)d_ws;
    const size_t WSZ = 1024ull * 1024 * 2;
    const size_t QSZ = 8192ull * 1024 * 2;
    const size_t BW = 4 * WSZ;
    ushort_t* WqT = (ushort_t*)(ws + 0 * WSZ);
    ushort_t* WkT = (ushort_t*)(ws + 1 * WSZ);
    ushort_t* WvT = (ushort_t*)(ws + 2 * WSZ);
    ushort_t* WoT = (ushort_t*)(ws + 3 * WSZ);
    // Buffer lifetime aliasing (max live = 4 activations = 75.5 MB total ws):
    ushort_t* S1 = (ushort_t*)(ws + BW + 0 * QSZ);  // Qbf  -> Kws
    ushort_t* S2 = (ushort_t*)(ws + BW + 1 * QSZ);  // Kbf  -> Vws
    ushort_t* S3 = (ushort_t*)(ws + BW + 2 * QSZ);  // Vbf  -> VtG
    ushort_t* S4 = (ushort_t*)(ws + BW + 3 * QSZ);  // Qws  (= Z)

    cast3<<<dim3(4096, 1, 3), 256, 0, stream>>>(query, key, value, S1, S2, S3);
    transpose4<<<dim3(16, 16, 4), 256, 0, stream>>>(Wq, Wk, Wv, Wo, WqT, WkT, WvT, WoT);

    dim3 gg(8, 64);
    // Q projection carries 1/sqrt(64) * log2(e): softmax runs in exp2 domain
    gemm_async<false><<<gg, 256, 0, stream>>>(S1, WqT, bq, S4, 8192, 1024, 1024, 0.125f * 1.4426950408889634f);
    gemm_async<false><<<gg, 256, 0, stream>>>(S2, WkT, bk, S1, 8192, 1024, 1024, 1.0f);
    gemm_async<false><<<gg, 256, 0, stream>>>(S3, WvT, bv, S2, 8192, 1024, 1024, 1.0f);

    vtrans<<<dim3(32, 64), 256, 0, stream>>>(S2, S3);

    attn_fwd<<<dim3(16, 64), 256, 0, stream>>>(S4, S1, S3, S4);

    gemm_async<true><<<gg, 256, 0, stream>>>(S4, WoT, bo, out, 8192, 1024, 1024, 1.0f);
}